// Round 2
// baseline (699.402 us; speedup 1.0000x reference)
//
#include <hip/hip_runtime.h>
#include <hip/hip_bf16.h>
#include <stdint.h>

#define NROW 8192
#define CD 128
#define SPLITK 8
#define KCHUNK (NROW / SPLITK)   // 1024
#define KSTEPS (KCHUNK / 32)     // 32 K-steps of 32 per block

typedef __bf16 bf16_t;
typedef __bf16 bf16x8 __attribute__((ext_vector_type(8)));
typedef float f32x4 __attribute__((ext_vector_type(4)));   // clang ext-vector: ok for nontemporal builtins

__device__ __forceinline__ f32x4 mfma16(bf16x8 a, bf16x8 b, f32x4 c) {
    return __builtin_amdgcn_mfma_f32_16x16x32_bf16(a, b, c, 0, 0, 0);
}

__device__ __forceinline__ bf16x8 load_cvt_bf16(const float* __restrict__ p) {
    f32x4 a0 = *(const f32x4*)p;
    f32x4 a1 = *(const f32x4*)(p + 4);
    bf16x8 r;
    r[0] = (bf16_t)a0.x; r[1] = (bf16_t)a0.y; r[2] = (bf16_t)a0.z; r[3] = (bf16_t)a0.w;
    r[4] = (bf16_t)a1.x; r[5] = (bf16_t)a1.y; r[6] = (bf16_t)a1.z; r[7] = (bf16_t)a1.w;
    return r;
}

// h = x @ W^T. 512 blocks x 1 wave (was 128 blocks = half the GPU idle).
// Each wave: 16 rows. Epilogue via private-LDS transpose:
// out fp32 coalesced float4, hT [c][n] bf16 coalesced 16B stores.
__global__ __launch_bounds__(64)
void h_kernel(const float* __restrict__ x, const float* __restrict__ W,
              bf16_t* __restrict__ hT, float* __restrict__ out)
{
    __shared__ __align__(16) float hs[16 * 128];   // 8 KB
    const int lane = threadIdx.x;
    const int m = lane & 15, q = lane >> 4;
    const int rb = blockIdx.x * 16;

    f32x4 acc[8] = {};
#pragma unroll
    for (int k0 = 0; k0 < CD; k0 += 32) {
        bf16x8 af = load_cvt_bf16(x + (size_t)(rb + m) * CD + k0 + q * 8);
#pragma unroll
        for (int c = 0; c < 8; ++c) {
            bf16x8 bv = load_cvt_bf16(W + (size_t)(c * 16 + m) * CD + k0 + q * 8);
            acc[c] = mfma16(af, bv, acc[c]);
        }
    }
#pragma unroll
    for (int c = 0; c < 8; ++c)
#pragma unroll
        for (int j = 0; j < 4; ++j)
            hs[(q * 4 + j) * 128 + c * 16 + m] = acc[c][j];
    __syncthreads();   // single wave: effectively just the lgkm drain

    float* dst = out + (size_t)rb * CD;
#pragma unroll
    for (int t = 0; t < 8; ++t) {
        int fi = t * 64 + lane;                 // 512 float4 = 16x128
        *(f32x4*)(dst + fi * 4) = *(const f32x4*)(hs + fi * 4);
    }
#pragma unroll
    for (int t = 0; t < 4; ++t) {
        int idx = t * 64 + lane;                // 256 chunks: 128 c x 2 n-chunks
        int c = idx >> 1, nc = idx & 1;
        bf16x8 v;
#pragma unroll
        for (int j = 0; j < 8; ++j)
            v[j] = (bf16_t)hs[(nc * 8 + j) * 128 + c];
        *(bf16x8*)(hT + (size_t)c * NROW + rb + nc * 8) = v;
    }
}

// out_partial = (adj .* mask) @ h for one K-chunk.
// Streaming design: NO LDS, NO barriers. A (adj*mask) has zero cross-wave
// reuse -> each lane loads its MFMA fragment directly from global (row rb+m,
// cols k+q*8: 64B-contiguous per row, full cache lines), multiplies and
// converts in registers. B (hT, 2 MB) is L2-resident per XCD -> fragments
// read straight from global. Register double-buffering (named bufs, static
// indexing); latency hiding via 12 waves/CU of independent TLP instead of
// barrier-drained pipelines. Nontemporal on the 512 MB adj/mask stream so it
// doesn't evict hT from L2; nt stores on the write-once partials.
template <bool ATOMIC>
__global__ __launch_bounds__(256)
void gemm_kernel(const float* __restrict__ adj, const float* __restrict__ mask,
                 const bf16_t* __restrict__ hT, float* __restrict__ outp)
{
    const int tid  = threadIdx.x;
    const int w    = tid >> 6;
    const int lane = tid & 63;
    const int m = lane & 15, q = lane >> 4;
    const int row  = blockIdx.x * 64 + w * 16 + m;   // this lane's adj/mask row
    const int kbeg = blockIdx.y * KCHUNK;

    const float*  pa = adj  + (size_t)row * NROW + kbeg + q * 8;
    const float*  pm = mask + (size_t)row * NROW + kbeg + q * 8;
    const bf16_t* pb = hT   + (size_t)m   * NROW + kbeg + q * 8;

    f32x4 acc[8] = {};

    f32x4 aA0, aA1, xA0, xA1, aB0, aB1, xB0, xB1;
    bf16x8 bA[8], bB[8];

    auto loadA = [&](int it, f32x4& a0, f32x4& a1, f32x4& x0, f32x4& x1) {
        const float* p0 = pa + it * 32;
        const float* p1 = pm + it * 32;
        a0 = __builtin_nontemporal_load((const f32x4*)p0);
        a1 = __builtin_nontemporal_load((const f32x4*)(p0 + 4));
        x0 = __builtin_nontemporal_load((const f32x4*)p1);
        x1 = __builtin_nontemporal_load((const f32x4*)(p1 + 4));
    };
    auto loadB = [&](int it, bf16x8* b) {
#pragma unroll
        for (int c = 0; c < 8; ++c)
            b[c] = *(const bf16x8*)(pb + (size_t)c * 16 * NROW + it * 32);
    };
    auto comp = [&](const f32x4& a0, const f32x4& a1,
                    const f32x4& x0, const f32x4& x1, const bf16x8* b) {
        bf16x8 af;
        af[0] = (bf16_t)(a0.x * x0.x);
        af[1] = (bf16_t)(a0.y * x0.y);
        af[2] = (bf16_t)(a0.z * x0.z);
        af[3] = (bf16_t)(a0.w * x0.w);
        af[4] = (bf16_t)(a1.x * x1.x);
        af[5] = (bf16_t)(a1.y * x1.y);
        af[6] = (bf16_t)(a1.z * x1.z);
        af[7] = (bf16_t)(a1.w * x1.w);
#pragma unroll
        for (int c = 0; c < 8; ++c)
            acc[c] = mfma16(af, b[c], acc[c]);
    };

    loadA(0, aA0, aA1, xA0, xA1);
    loadB(0, bA);
#pragma unroll
    for (int it = 0; it < KSTEPS / 2; ++it) {      // 16 bodies, fully unrolled
        loadA(2 * it + 1, aB0, aB1, xB0, xB1);
        loadB(2 * it + 1, bB);
        comp(aA0, aA1, xA0, xA1, bA);
        if (it + 1 < KSTEPS / 2) {
            loadA(2 * it + 2, aA0, aA1, xA0, xA1);
            loadB(2 * it + 2, bA);
        }
        comp(aB0, aB1, xB0, xB1, bB);
    }

    // Epilogue: acc[c][j] = out[row = q*4+j][col = c*16+m] within the wave's
    // 16x128 tile. Scalar stores land in 4 x 64B contiguous segments per
    // instruction -> full cache lines, no LDS transpose needed.
    if (!ATOMIC) {
        float* dst = outp + (size_t)blockIdx.y * ((size_t)NROW * CD)
                   + (size_t)(blockIdx.x * 64 + w * 16) * CD;
#pragma unroll
        for (int c = 0; c < 8; ++c)
#pragma unroll
            for (int j = 0; j < 4; ++j)
                __builtin_nontemporal_store(acc[c][j],
                    dst + (q * 4 + j) * CD + c * 16 + m);
    } else {
        float* dst = outp + (size_t)(blockIdx.x * 64 + w * 16) * CD;
#pragma unroll
        for (int c = 0; c < 8; ++c)
#pragma unroll
            for (int j = 0; j < 4; ++j)
                atomicAdd(dst + (q * 4 + j) * CD + c * 16 + m, acc[c][j]);
    }
}

// out = out(h contribution) + sum over split-K partials
__global__ void reduce_kernel(float* __restrict__ out, const float* __restrict__ part)
{
    const size_t i = ((size_t)blockIdx.x * 256 + threadIdx.x) * 4;
    f32x4 sum = *(const f32x4*)(out + i);
#pragma unroll
    for (int sp = 0; sp < SPLITK; ++sp) {
        f32x4 p = __builtin_nontemporal_load(
            (const f32x4*)(part + (size_t)sp * ((size_t)NROW * CD) + i));
        sum += p;
    }
    *(f32x4*)(out + i) = sum;
}

extern "C" void kernel_launch(void* const* d_in, const int* in_sizes, int n_in,
                              void* d_out, int out_size, void* d_ws, size_t ws_size,
                              hipStream_t stream)
{
    const float* x    = (const float*)d_in[0];
    const float* adj  = (const float*)d_in[1];
    const float* mask = (const float*)d_in[2];
    const float* W    = (const float*)d_in[3];
    float* out = (float*)d_out;

    bf16_t* hT = (bf16_t*)d_ws;  // 128 x 8192 bf16 = 2 MB
    const size_t HT_BYTES   = (size_t)CD * NROW * sizeof(bf16_t);
    const size_t PART_BYTES = (size_t)SPLITK * NROW * CD * sizeof(float);  // 32 MB

    h_kernel<<<dim3(NROW / 16), dim3(64), 0, stream>>>(x, W, hT, out);

    if (ws_size >= HT_BYTES + PART_BYTES) {
        float* part = (float*)((char*)d_ws + HT_BYTES);
        gemm_kernel<false><<<dim3(NROW / 64, SPLITK), dim3(256), 0, stream>>>(adj, mask, hT, part);
        reduce_kernel<<<dim3(1024), dim3(256), 0, stream>>>(out, part);
    } else {
        gemm_kernel<true><<<dim3(NROW / 64, SPLITK), dim3(256), 0, stream>>>(adj, mask, hT, out);
    }
}

// Round 3
// 636.804 us; speedup vs baseline: 1.0983x; 1.0983x over previous
//
#include <hip/hip_runtime.h>
#include <hip/hip_bf16.h>
#include <stdint.h>

#define NROW 8192
#define CD 128
#define SPLITK 4
#define KCHUNK (NROW / SPLITK)   // 2048
#define BK2 256
#define ROUNDS (KCHUNK / BK2)    // 8

typedef __bf16 bf16_t;
typedef __bf16 bf16x8 __attribute__((ext_vector_type(8)));
typedef __bf16 bf16x4 __attribute__((ext_vector_type(4)));
typedef float f32x4 __attribute__((ext_vector_type(4)));

__device__ __forceinline__ f32x4 mfma16(bf16x8 a, bf16x8 b, f32x4 c) {
    return __builtin_amdgcn_mfma_f32_16x16x32_bf16(a, b, c, 0, 0, 0);
}

__device__ __forceinline__ bf16x8 load_cvt_bf16(const float* __restrict__ p) {
    f32x4 a0 = *(const f32x4*)p;
    f32x4 a1 = *(const f32x4*)(p + 4);
    bf16x8 r;
    r[0] = (bf16_t)a0.x; r[1] = (bf16_t)a0.y; r[2] = (bf16_t)a0.z; r[3] = (bf16_t)a0.w;
    r[4] = (bf16_t)a1.x; r[5] = (bf16_t)a1.y; r[6] = (bf16_t)a1.z; r[7] = (bf16_t)a1.w;
    return r;
}

// h = x @ W^T. Round-0 proven version: 128 blocks x 4 waves, 16 rows/wave.
// Epilogue via private-LDS transpose: out fp32 coalesced float4,
// hT [c][n] bf16 coalesced 16B stores.
__global__ __launch_bounds__(256)
void h_kernel(const float* __restrict__ x, const float* __restrict__ W,
              bf16_t* __restrict__ hT, float* __restrict__ out)
{
    __shared__ __align__(16) float h_sl_all[4][16 * 128];  // 32 KB
    const int tid = threadIdx.x;
    const int w = tid >> 6, lane = tid & 63;
    const int m = lane & 15, q = lane >> 4;
    const int rb = blockIdx.x * 64 + w * 16;   // wave's 16 rows

    f32x4 acc[8] = {};
#pragma unroll
    for (int k0 = 0; k0 < CD; k0 += 32) {
        bf16x8 af = load_cvt_bf16(x + (size_t)(rb + m) * CD + k0 + q * 8);
#pragma unroll
        for (int c = 0; c < 8; ++c) {
            bf16x8 bv = load_cvt_bf16(W + (size_t)(c * 16 + m) * CD + k0 + q * 8);
            acc[c] = mfma16(af, bv, acc[c]);
        }
    }
    float* hs = h_sl_all[w];
#pragma unroll
    for (int c = 0; c < 8; ++c)
#pragma unroll
        for (int j = 0; j < 4; ++j)
            hs[(q * 4 + j) * 128 + c * 16 + m] = acc[c][j];
    // per-wave private LDS region; compiler inserts lgkmcnt before reads

    float* dst = out + (size_t)rb * CD;
#pragma unroll
    for (int t = 0; t < 8; ++t) {
        int fi = t * 64 + lane;                 // 512 float4 = 16x128
        *(f32x4*)(dst + fi * 4) = *(const f32x4*)(hs + fi * 4);
    }
#pragma unroll
    for (int t = 0; t < 4; ++t) {
        int idx = t * 64 + lane;                // 256 chunks: 128 c x 2 n-chunks
        int c = idx >> 1, nc = idx & 1;
        bf16x8 v;
#pragma unroll
        for (int j = 0; j < 8; ++j)
            v[j] = (bf16_t)hs[(nc * 8 + j) * 128 + c];
        *(bf16x8*)(hT + (size_t)c * NROW + rb + nc * 8) = v;
    }
}

// out_partial = (adj .* mask) @ h for one K-chunk.
// DRAM-efficiency design: every A-load instruction reads 1 KB CONTIGUOUS from
// a single adj/mask row (64 lanes x 16 B), instead of 64 B touches scattered
// over 16 rows (round 2: 1.85 TB/s from page thrashing). Wave stages its 16
// rows (adj*mask -> bf16) into a double-buffered 2x32 KB LDS tile with the
// round-0 XOR-granule swizzle (measured 0 bank conflicts). B (hT, 2 MB) is
// L2-resident and read direct from global. Two staging groups of 8 rows are
// interleaved with the two compute halves so HBM latency hides under MFMA.
template <bool ATOMIC>
__global__ __launch_bounds__(256, 2)
void gemm_kernel(const float* __restrict__ adj, const float* __restrict__ mask,
                 const bf16_t* __restrict__ hT, float* __restrict__ outp)
{
    __shared__ __align__(16) ushort prod[2][64 * 256];   // 2 x 32 KB bf16 product

    const int tid  = threadIdx.x;
    const int w    = tid >> 6;
    const int lane = tid & 63;
    const int m = lane & 15, q = lane >> 4;
    const int rowbase = blockIdx.x * 64;
    const int kbeg = blockIdx.y * KCHUNK;

    const bf16_t* pb = hT + (size_t)m * NROW + kbeg + q * 8;

    f32x4 acc[8] = {};
    f32x4 vaA[8], vxA[8], vaB[8], vxB[8];

    // 8 rows of adj+mask: one full-row 1 KB load per instruction
    auto issueG = [&](int it, int g, f32x4* va, f32x4* vx) {
        const int kw = kbeg + it * BK2;
#pragma unroll
        for (int rr = 0; rr < 8; ++rr) {
            int row = w * 16 + g * 8 + rr;
            const float* pA = adj  + (size_t)(rowbase + row) * NROW + kw + lane * 4;
            const float* pM = mask + (size_t)(rowbase + row) * NROW + kw + lane * 4;
            va[rr] = *(const f32x4*)pA;
            vx[rr] = *(const f32x4*)pM;
        }
    };
    // multiply, cvt to bf16, swizzled 8B LDS writes
    auto processG = [&](int g, ushort* buf, const f32x4* va, const f32x4* vx) {
#pragma unroll
        for (int rr = 0; rr < 8; ++rr) {
            int row = w * 16 + g * 8 + rr;
            bf16x4 p;
            p[0] = (bf16_t)(va[rr].x * vx[rr].x);
            p[1] = (bf16_t)(va[rr].y * vx[rr].y);
            p[2] = (bf16_t)(va[rr].z * vx[rr].z);
            p[3] = (bf16_t)(va[rr].w * vx[rr].w);
            *(bf16x4*)(buf + row * 256 + (((lane >> 1) ^ (row & 7)) << 3)
                       + (lane & 1) * 4) = p;
        }
    };
    // 4 K-steps of 32: swizzled A-fragment from LDS, B direct from L2-resident hT
    auto computeH = [&](const ushort* buf, int it, int h) {
#pragma unroll
        for (int s = 0; s < 4; ++s) {
            int ks = h * 4 + s;
            bf16x8 af = *(const bf16x8*)(buf + (w * 16 + m) * 256
                                         + (((ks * 4 + q) ^ (m & 7)) << 3));
#pragma unroll
            for (int c = 0; c < 8; ++c) {
                bf16x8 bv = *(const bf16x8*)(pb + (size_t)c * 16 * NROW
                                             + it * BK2 + ks * 32);
                acc[c] = mfma16(af, bv, acc[c]);
            }
        }
    };

    // prologue: stage round 0 (sequential groups keep VGPR high-water bounded)
    issueG(0, 0, vaA, vxA);
    processG(0, (ushort*)prod[0], vaA, vxA);
    issueG(0, 1, vaB, vxB);
    processG(1, (ushort*)prod[0], vaB, vxB);

    for (int it = 0; it < ROUNDS; ++it) {
        __syncthreads();                      // buf[it&1] writes visible
        const bool nx = it + 1 < ROUNDS;
        const ushort* cur = prod[it & 1];
        ushort* nxt = (ushort*)prod[(it + 1) & 1];
        if (nx) issueG(it + 1, 0, vaA, vxA);  // HBM loads in flight...
        computeH(cur, it, 0);                 // ...under 32 MFMAs
        if (nx) { processG(0, nxt, vaA, vxA); issueG(it + 1, 1, vaB, vxB); }
        computeH(cur, it, 1);
        if (nx) processG(1, nxt, vaB, vxB);
    }

    // Epilogue: acc[c][j] = out[row = q*4+j][col = c*16+m] in the wave's
    // 16x128 tile; stores merge to full lines in L2.
    if (!ATOMIC) {
        float* dst = outp + (size_t)blockIdx.y * ((size_t)NROW * CD)
                   + (size_t)(rowbase + w * 16) * CD;
#pragma unroll
        for (int c = 0; c < 8; ++c)
#pragma unroll
            for (int j = 0; j < 4; ++j)
                dst[(q * 4 + j) * CD + c * 16 + m] = acc[c][j];
    } else {
        float* dst = outp + (size_t)(rowbase + w * 16) * CD;
#pragma unroll
        for (int c = 0; c < 8; ++c)
#pragma unroll
            for (int j = 0; j < 4; ++j)
                atomicAdd(dst + (q * 4 + j) * CD + c * 16 + m, acc[c][j]);
    }
}

// out = out(h contribution) + sum over split-K partials
__global__ void reduce_kernel(float* __restrict__ out, const float* __restrict__ part)
{
    const size_t i = ((size_t)blockIdx.x * 256 + threadIdx.x) * 4;
    f32x4 sum = *(const f32x4*)(out + i);
#pragma unroll
    for (int sp = 0; sp < SPLITK; ++sp) {
        f32x4 p = *(const f32x4*)(part + (size_t)sp * ((size_t)NROW * CD) + i);
        sum += p;
    }
    *(f32x4*)(out + i) = sum;
}

extern "C" void kernel_launch(void* const* d_in, const int* in_sizes, int n_in,
                              void* d_out, int out_size, void* d_ws, size_t ws_size,
                              hipStream_t stream)
{
    const float* x    = (const float*)d_in[0];
    const float* adj  = (const float*)d_in[1];
    const float* mask = (const float*)d_in[2];
    const float* W    = (const float*)d_in[3];
    float* out = (float*)d_out;

    bf16_t* hT = (bf16_t*)d_ws;  // 128 x 8192 bf16 = 2 MB
    const size_t HT_BYTES   = (size_t)CD * NROW * sizeof(bf16_t);
    const size_t PART_BYTES = (size_t)SPLITK * NROW * CD * sizeof(float);  // 16 MB

    h_kernel<<<dim3(NROW / 64), dim3(256), 0, stream>>>(x, W, hT, out);

    if (ws_size >= HT_BYTES + PART_BYTES) {
        float* part = (float*)((char*)d_ws + HT_BYTES);
        gemm_kernel<false><<<dim3(NROW / 64, SPLITK), dim3(256), 0, stream>>>(adj, mask, hT, part);
        reduce_kernel<<<dim3(1024), dim3(256), 0, stream>>>(out, part);
    } else {
        gemm_kernel<true><<<dim3(NROW / 64, SPLITK), dim3(256), 0, stream>>>(adj, mask, hT, out);
    }
}